// Round 4
// baseline (541.673 us; speedup 1.0000x reference)
//
#include <hip/hip_runtime.h>

#define N_TOK 16384
#define HID   4096
#define N_EXP 64
#define TOPK  8

// d_out layout (floats, concatenated in reference return order)
#define OFF_WT   (N_TOK * N_EXP)
#define OFF_IDX  (OFF_WT + N_TOK * TOPK)
#define OFF_MASK (OFF_IDX + N_TOK * TOPK)

typedef __attribute__((ext_vector_type(8))) _Float16 f16x8;
typedef __attribute__((ext_vector_type(4))) float f32x4;

// split f into f16 hi (RNE) + f16 lo (RNE of residual): hi+lo ~ f, rel err 2^-24
static __device__ __forceinline__ void hsplit(float f, unsigned short &h, unsigned short &l)
{
    _Float16 hh = (_Float16)f;
    float r = f - (float)hh;
    _Float16 hl = (_Float16)r;
    h = __builtin_bit_cast(unsigned short, hh);
    l = __builtin_bit_cast(unsigned short, hl);
}

// ---------------------------------------------------------------------------
// Kernel 0: split W (fp32 [64][4096]) into f16 hi/lo planes in workspace.
// ---------------------------------------------------------------------------
__global__ __launch_bounds__(256)
void prep_w(const float* __restrict__ W,
            unsigned short* __restrict__ wh, unsigned short* __restrict__ wl)
{
    const int i = blockIdx.x * 256 + threadIdx.x;     // 65536 float4s
    float4 f = ((const float4*)W)[i];
    unsigned short h0,l0,h1,l1,h2,l2,h3,l3;
    hsplit(f.x,h0,l0); hsplit(f.y,h1,l1); hsplit(f.z,h2,l2); hsplit(f.w,h3,l3);
    *(uint2*)&wh[4*i] = make_uint2((unsigned)h0 | ((unsigned)h1<<16), (unsigned)h2 | ((unsigned)h3<<16));
    *(uint2*)&wl[4*i] = make_uint2((unsigned)l0 | ((unsigned)l1<<16), (unsigned)l2 | ((unsigned)l3<<16));
}

// ---------------------------------------------------------------------------
// Kernel A: f16x3 MFMA GEMM, NO LDS / NO BARRIERS. router = x @ W^T + b.
// Block = 16 tokens x 64 experts, 4 waves (one 16-expert group each).
// Grid 1024 -> 4 blocks/CU, 16 waves/CU: latency hidden by TLP.
// Fragments loaded straight from global: x rows (HBM stream, L1-shared by
// the 4 waves), W planes (1 MB, L1/L2-resident). Register double-buffer,
// static indexing (two named sets A/B), f16x3: xh.wh + xh.wl + xl.wh.
// ---------------------------------------------------------------------------
__global__ __launch_bounds__(256, 4)
void router_gemm(const float* __restrict__ x,
                 const unsigned short* __restrict__ wh,
                 const unsigned short* __restrict__ wl,
                 const float* __restrict__ b,
                 float* __restrict__ router)
{
    const int tid  = threadIdx.x;
    const int lane = tid & 63, wv = tid >> 6;
    const long t0  = (long)blockIdx.x * 16;
    const int  e0  = wv * 16;
    const int  lrow = lane & 15, lg = lane >> 4;

    // per-lane fragment base pointers (A: token row, B: expert row)
    const float*          xp  = x  + (t0 + lrow) * (long)HID + lg * 8;
    const unsigned short* whp = wh + (long)(e0 + lrow) * HID + lg * 8;
    const unsigned short* wlp = wl + (long)(e0 + lrow) * HID + lg * 8;

    f32x4 acc = {};

    // one stage = 64 k-elems: per lane x 16 floats (2 ks x 32B), W 2x(16B hi+lo)
    auto LOAD = [&](int st, float4 (&xv)[4], uint4 (&hv)[2], uint4 (&lv)[2]) {
        const long o = (long)st * 64;
        xv[0] = *(const float4*)(xp + o);
        xv[1] = *(const float4*)(xp + o + 4);
        xv[2] = *(const float4*)(xp + o + 32);
        xv[3] = *(const float4*)(xp + o + 36);
        hv[0] = *(const uint4*)(whp + o);
        hv[1] = *(const uint4*)(whp + o + 32);
        lv[0] = *(const uint4*)(wlp + o);
        lv[1] = *(const uint4*)(wlp + o + 32);
    };

    auto COMP = [&](const float4 (&xv)[4], const uint4 (&hv)[2], const uint4 (&lv)[2]) {
#pragma unroll
        for (int ks = 0; ks < 2; ++ks) {
            float xf[8];
            *(float4*)&xf[0] = xv[2 * ks];
            *(float4*)&xf[4] = xv[2 * ks + 1];
            f16x8 ah, al;
#pragma unroll
            for (int j = 0; j < 8; ++j) {
                _Float16 h = (_Float16)xf[j];
                ah[j] = h;
                al[j] = (_Float16)(xf[j] - (float)h);
            }
            const f16x8 bh = __builtin_bit_cast(f16x8, hv[ks]);
            const f16x8 bl = __builtin_bit_cast(f16x8, lv[ks]);
            acc = __builtin_amdgcn_mfma_f32_16x16x32_f16(ah, bh, acc, 0, 0, 0);
            acc = __builtin_amdgcn_mfma_f32_16x16x32_f16(ah, bl, acc, 0, 0, 0);
            acc = __builtin_amdgcn_mfma_f32_16x16x32_f16(al, bh, acc, 0, 0, 0);
        }
    };

    float4 xA[4], xB[4];
    uint4  hA[2], hB[2], lA[2], lB[2];

    LOAD(0, xA, hA, lA);
    LOAD(1, xB, hB, lB);

#pragma unroll 1
    for (int st = 0; st < HID / 64; st += 2) {
        COMP(xA, hA, lA);
        if (st + 2 < HID / 64) LOAD(st + 2, xA, hA, lA);
        COMP(xB, hB, lB);
        if (st + 3 < HID / 64) LOAD(st + 3, xB, hB, lB);
    }

    // epilogue: C layout col=lane&15 (expert), row=(lane>>4)*4+r (token)
    const int e = e0 + lrow;
    const float bias = b[e];
#pragma unroll
    for (int r = 0; r < 4; ++r) {
        const long tok = t0 + lg * 4 + r;
        router[tok * N_EXP + e] = acc[r] + bias;
    }
}

// ---------------------------------------------------------------------------
// Kernel B: softmax + top-8 (tie -> lowest index) + renorm weights + indices.
// Wave per token. Logits already include bias.
// ---------------------------------------------------------------------------
__global__ __launch_bounds__(256)
void router_topk(const float* __restrict__ router, float* __restrict__ out)
{
    const int tid  = threadIdx.x;
    const int lane = tid & 63;
    const int wv   = tid >> 6;
    const int n    = blockIdx.x * 4 + wv;

    float l = router[(long)n * N_EXP + lane];

    float m = l;
#pragma unroll
    for (int o = 32; o > 0; o >>= 1) m = fmaxf(m, __shfl_xor(m, o));
    float p = expf(l - m);
    float Z = p;
#pragma unroll
    for (int o = 32; o > 0; o >>= 1) Z += __shfl_xor(Z, o);
    float prob = p / Z;

    float cur = prob;
    float myv = 0.f;
    int   myi = 0;
    float ssum = 0.f;
#pragma unroll
    for (int k = 0; k < TOPK; ++k) {
        float v = cur;
        int   id = lane;
#pragma unroll
        for (int o = 32; o > 0; o >>= 1) {
            float ov = __shfl_xor(v, o);
            int   oi = __shfl_xor(id, o);
            if (ov > v || (ov == v && oi < id)) { v = ov; id = oi; }
        }
        if (lane == k)  { myv = v; myi = id; }
        if (lane == id) cur = -1.f;
        ssum += v;
    }

    if (lane < TOPK) {
        out[OFF_WT  + (long)n * TOPK + lane] = myv / ssum;
        out[OFF_IDX + (long)n * TOPK + lane] = (float)myi;
    }
}

// ---------------------------------------------------------------------------
// Kernel C: full coalesced one-hot mask write: mask[e][k][n] = (idx[n][k]==e).
// Every mask element written exactly once (no memset needed).
// ---------------------------------------------------------------------------
__global__ __launch_bounds__(256)
void mask_fill(const float* __restrict__ idxf, float* __restrict__ mask)
{
    const int bid = blockIdx.x;           // 2048 blocks
    const int ek  = bid >> 2, qtr = bid & 3;
    const int k   = ek & 7;
    const float fe = (float)(ek >> 3);
    float* mbase = mask + (long)ek * N_TOK;
#pragma unroll
    for (int j = 0; j < 4; ++j) {
        const int n = qtr * 4096 + j * 1024 + threadIdx.x * 4;
        float4 v;
        v.x = (idxf[(long)(n + 0) * TOPK + k] == fe) ? 1.f : 0.f;
        v.y = (idxf[(long)(n + 1) * TOPK + k] == fe) ? 1.f : 0.f;
        v.z = (idxf[(long)(n + 2) * TOPK + k] == fe) ? 1.f : 0.f;
        v.w = (idxf[(long)(n + 3) * TOPK + k] == fe) ? 1.f : 0.f;
        *(float4*)&mbase[n] = v;
    }
}

extern "C" void kernel_launch(void* const* d_in, const int* in_sizes, int n_in,
                              void* d_out, int out_size, void* d_ws, size_t ws_size,
                              hipStream_t stream)
{
    const float* x = (const float*)d_in[0];
    const float* W = (const float*)d_in[1];
    const float* b = (const float*)d_in[2];
    float* out = (float*)d_out;

    unsigned short* wsh = (unsigned short*)d_ws;              // W hi plane (512 KB)
    unsigned short* wsl = wsh + (size_t)N_EXP * HID;          // W lo plane (512 KB)

    // no memset: router fully written by GEMM, wt/idx by topk, mask by mask_fill
    hipLaunchKernelGGL(prep_w,      dim3(N_EXP * HID / 1024), dim3(256), 0, stream, W, wsh, wsl);
    hipLaunchKernelGGL(router_gemm, dim3(N_TOK / 16),         dim3(256), 0, stream, x, wsh, wsl, b, out);
    hipLaunchKernelGGL(router_topk, dim3(N_TOK / 4),          dim3(256), 0, stream, out, out);
    hipLaunchKernelGGL(mask_fill,   dim3(N_EXP * TOPK * 4),   dim3(256), 0, stream,
                       out + OFF_IDX, out + OFF_MASK);
}